// Round 9
// baseline (181.856 us; speedup 1.0000x reference)
//
#include <hip/hip_runtime.h>
#include <stdint.h>

#define Bn 16
#define Sn 2048
#define Dn 128
#define QBLK 64
#define KVBLK 64
#define NTHR 256
#define NT 32

typedef __attribute__((ext_vector_type(4))) float f32x4;
typedef __attribute__((ext_vector_type(16))) float f32x16;
typedef __attribute__((ext_vector_type(8))) short bf16x8;   // 8 bf16 = 4 VGPRs
typedef __attribute__((ext_vector_type(2))) unsigned int u32x2;

// LDS: double-buffered shared tile, 34304 B per buffer:
//  K  : [64] rows stride 264 B  byte(k,d) = k*264 + 2d   (2-way banks, free)
//  VT : [128] rows stride 136 B byte(d,k) = d*136 + 2k   (2-way banks)
// Epilogue exchange regions overlay the buffers (post-loop only).
#define KSTRIDE 264
#define VTOFF 16896
#define VSTRIDE 136
#define BUFSZ 34304
#define SMEM_BYTES (2 * BUFSZ)   // 68608

__device__ __forceinline__ uint32_t f2bf_u(float f) {   // fp32 -> bf16, round-nearest-away
  return (__float_as_uint(f) + 0x8000u) >> 16;
}
__device__ __forceinline__ uint32_t pk2(float a, float b) {
  return f2bf_u(a) | (f2bf_u(b) << 16);
}

__global__ __launch_bounds__(NTHR, 2) void attn_fwd(
    const float* __restrict__ Q, const float* __restrict__ K,
    const float* __restrict__ V, float* __restrict__ O) {
  __shared__ uint4 smem_[SMEM_BYTES / 16];
  char* smem = (char*)smem_;

  const int tid = threadIdx.x;
  const int lane = tid & 63;
  const int w = tid >> 6;        // wave 0..3
  const int qw = w & 1;          // q sub-tile (32 rows)
  const int h = w >> 1;          // k sub-range of each tile (32 rows)
  const int hi = lane >> 5;      // half-wave 0/1
  const int ql = lane & 31;      // q / k-row / d-row selector
  const int b = blockIdx.y;
  const int q0 = blockIdx.x * QBLK;
  const int qg = q0 + qw * 32 + ql;
  const int vm = tid & 127;      // V staging: column owned
  const int vkh = tid >> 7;      // V staging: k-half 0/1

  // ---- Q in registers: B-operand of swapped QK^T. col=q=lane&31, kd=8*hi+j ----
  const float qscale = 0.08838834764831845f * 1.44269504088896340736f; // 1/sqrt(128)*log2e
  bf16x8 qf[8];
  {
    const float* qrow = Q + (size_t)(b * Sn + qg) * Dn;
#pragma unroll
    for (int dk = 0; dk < 8; ++dk) {
      const int d0 = dk * 16 + hi * 8;
      const float4 a = *(const float4*)(qrow + d0);
      const float4 d = *(const float4*)(qrow + d0 + 4);
      bf16x8 q8;
      q8[0] = (short)f2bf_u(a.x * qscale); q8[1] = (short)f2bf_u(a.y * qscale);
      q8[2] = (short)f2bf_u(a.z * qscale); q8[3] = (short)f2bf_u(a.w * qscale);
      q8[4] = (short)f2bf_u(d.x * qscale); q8[5] = (short)f2bf_u(d.y * qscale);
      q8[6] = (short)f2bf_u(d.z * qscale); q8[7] = (short)f2bf_u(d.w * qscale);
      qf[dk] = q8;
    }
  }

  // O^T accumulators over this wave's k-subset: col=q=lane&31
  f32x16 o[4];
#pragma unroll
  for (int dt = 0; dt < 4; ++dt) {
#pragma unroll
    for (int j = 0; j < 16; ++j) o[dt][j] = 0.f;
  }
  float m_r = -1.0e30f, l_r = 0.f;

  const float4* Kg4 = (const float4*)(K + (size_t)b * Sn * Dn);
  const float* Vg_base = V + (size_t)b * Sn * Dn;

  float4 kreg[8];
  float vreg[32];

#define ISSUE_K(kv_)                                                           \
  {                                                                            \
    const int kvrow4 = (kv_) * (Dn / 4);                                       \
    _Pragma("unroll") for (int it = 0; it < 8; ++it) {                         \
      const int gr = it * NTHR + tid;                                          \
      kreg[it] = Kg4[kvrow4 + (gr >> 5) * 32 + (gr & 31)];                     \
    }                                                                          \
  }
#define COMMIT_K(dst_)                                                         \
  {                                                                            \
    _Pragma("unroll") for (int it = 0; it < 8; ++it) {                         \
      const int gr = it * NTHR + tid;                                          \
      const int k = gr >> 5, dg = gr & 31;                                     \
      u32x2 wv;                                                                \
      wv.x = pk2(kreg[it].x, kreg[it].y);                                      \
      wv.y = pk2(kreg[it].z, kreg[it].w);                                      \
      *(u32x2*)(smem + (dst_) + k * KSTRIDE + dg * 8) = wv;                    \
    }                                                                          \
  }
#define ISSUE_V(kv_)                                                           \
  {                                                                            \
    const float* Vg = Vg_base + (size_t)(kv_)*Dn;                              \
    _Pragma("unroll") for (int j = 0; j < 32; ++j)                             \
        vreg[j] = Vg[(vkh * 32 + j) * Dn + vm];                                \
  }
#define COMMIT_V(dst_)                                                         \
  {                                                                            \
    _Pragma("unroll") for (int i = 0; i < 4; ++i) {                            \
      uint4 pk;                                                                \
      pk.x = pk2(vreg[8 * i + 0], vreg[8 * i + 1]);                            \
      pk.y = pk2(vreg[8 * i + 2], vreg[8 * i + 3]);                            \
      pk.z = pk2(vreg[8 * i + 4], vreg[8 * i + 5]);                            \
      pk.w = pk2(vreg[8 * i + 6], vreg[8 * i + 7]);                            \
      *(uint4*)(smem + (dst_) + VTOFF + vm * VSTRIDE + vkh * 64 + i * 16) = pk;\
    }                                                                          \
  }

  // prologue: stage tile 0 into buf 0
  ISSUE_K(0)
  COMMIT_K(0)
  ISSUE_V(0)
  COMMIT_V(0)
  __syncthreads();

  for (int t = 0; t < NT; ++t) {
    const uint32_t cb = (uint32_t)(t & 1) * BUFSZ;
    const uint32_t nb = BUFSZ - cb;
    const bool pf = (t < NT - 1);

    // issue next tile's loads; latency hides under this tile's compute
    if (pf) {
      ISSUE_K((t + 1) * KVBLK)
      ISSUE_V((t + 1) * KVBLK)
    }

    // ---- swapped QK^T: S^T[k'][q], k' = this wave's 32-row k-subset ----
    f32x16 s;
#pragma unroll
    for (int j = 0; j < 16; ++j) s[j] = 0.f;
    __builtin_amdgcn_s_setprio(1);
#pragma unroll
    for (int dk = 0; dk < 8; ++dk) {
      bf16x8 a = *(const bf16x8*)(smem + cb + (32 * h + ql) * KSTRIDE +
                                  dk * 32 + hi * 16);
      s = __builtin_amdgcn_mfma_f32_32x32x16_bf16(a, qf[dk], s, 0, 0, 0);
    }
    __builtin_amdgcn_s_setprio(0);
    // lane holds, for q=ql: k' = 32h + (r&3) + 8*(r>>2) + 4*hi, r=0..15

    if (pf) COMMIT_K(nb)

    // ---- in-register online softmax (per-wave-independent m,l over its k') ----
    float x0 = fmaxf(fmaxf(s[0], s[1]), fmaxf(s[2], s[3]));
    float x1 = fmaxf(fmaxf(s[4], s[5]), fmaxf(s[6], s[7]));
    float x2 = fmaxf(fmaxf(s[8], s[9]), fmaxf(s[10], s[11]));
    float x3 = fmaxf(fmaxf(s[12], s[13]), fmaxf(s[14], s[15]));
    float pm = fmaxf(fmaxf(x0, x1), fmaxf(x2, x3));
    pm = fmaxf(pm, __shfl_xor(pm, 32, 64));   // combine hi-halves

    if (!__all(pm <= m_r + 8.0f)) {   // defer-max (T13)
      const float mnew = fmaxf(m_r, pm);
      const float alpha = __builtin_amdgcn_exp2f(m_r - mnew);
      l_r *= alpha;
#pragma unroll
      for (int dt = 0; dt < 4; ++dt) o[dt] *= alpha;
      m_r = mnew;
    }

    float p[16];
#pragma unroll
    for (int j = 0; j < 16; ++j) p[j] = __builtin_amdgcn_exp2f(s[j] - m_r);
    {
      float r0 = 0.f, r1 = 0.f, r2 = 0.f, r3 = 0.f;
#pragma unroll
      for (int j = 0; j < 4; ++j) {
        r0 += p[j]; r1 += p[4 + j]; r2 += p[8 + j]; r3 += p[12 + j];
      }
      float rsum = (r0 + r1) + (r2 + r3);
      l_r += rsum + __shfl_xor(rsum, 32, 64);
    }

    // ---- pack P to bf16 + half-exchange with lane^32 -> PV B-fragments ----
    uint32_t own[4][2];
#pragma unroll
    for (int mm = 0; mm < 4; ++mm) {
      own[mm][0] = pk2(p[4 * mm + 0], p[4 * mm + 1]);
      own[mm][1] = pk2(p[4 * mm + 2], p[4 * mm + 3]);
    }
    uint32_t rcv[2][2];
#pragma unroll
    for (int jj = 0; jj < 2; ++jj)
#pragma unroll
      for (int e = 0; e < 2; ++e) {
        uint32_t sel = hi ? own[2 * jj][e] : own[2 * jj + 1][e];
        rcv[jj][e] = (uint32_t)__shfl_xor((int)sel, 32, 64);
      }
    bf16x8 pb[2];
#pragma unroll
    for (int ks = 0; ks < 2; ++ks) {
      union { uint32_t u[4]; bf16x8 v; } tt;
      tt.u[0] = hi ? rcv[ks][0] : own[2 * ks][0];
      tt.u[1] = hi ? rcv[ks][1] : own[2 * ks][1];
      tt.u[2] = hi ? own[2 * ks + 1][0] : rcv[ks][0];
      tt.u[3] = hi ? own[2 * ks + 1][1] : rcv[ks][1];
      pb[ks] = tt.v;
    }

    // ---- PV as O^T = V^T·P^T over this wave's k': A = VT rows (d) ----
    __builtin_amdgcn_s_setprio(1);
#pragma unroll
    for (int dt = 0; dt < 4; ++dt) {
      const uint32_t vbase =
          (uint32_t)(cb + VTOFF + (dt * 32 + ql) * VSTRIDE + h * 64 + hi * 16);
#pragma unroll
      for (int ks = 0; ks < 2; ++ks) {
        bf16x8 a = *(const bf16x8*)(smem + vbase + ks * 32);
        o[dt] = __builtin_amdgcn_mfma_f32_32x32x16_bf16(a, pb[ks], o[dt], 0, 0, 0);
      }
    }
    __builtin_amdgcn_s_setprio(0);

    if (pf) COMMIT_V(nb)

    __syncthreads();   // commits visible; everyone done reading buf[cb]
  }

  // ---- merge the two k-subset partials (w <-> w^2) in LDS, then store ----
  char* xch = smem + qw * 17408;
  if (h) {                       // k-half 1: writer
#pragma unroll
    for (int dt = 0; dt < 4; ++dt) {
#pragma unroll
      for (int q2 = 0; q2 < 4; ++q2) {
        float4 v;
        v.x = o[dt][4 * q2 + 0]; v.y = o[dt][4 * q2 + 1];
        v.z = o[dt][4 * q2 + 2]; v.w = o[dt][4 * q2 + 3];
        *(float4*)(xch + (dt * 4 + q2) * 1024 + lane * 16) = v;
      }
    }
    *(float2*)(xch + 16384 + lane * 8) = make_float2(m_r, l_r);
  }
  __syncthreads();
  if (!h) {                      // k-half 0: merger + storer
    const float2 ml1 = *(const float2*)(xch + 16384 + lane * 8);
    const float M = fmaxf(m_r, ml1.x);
    float w0 = __builtin_amdgcn_exp2f(m_r - M);
    float w1 = __builtin_amdgcn_exp2f(ml1.x - M);
    const float inv = 1.0f / (l_r * w0 + ml1.y * w1);
    w0 *= inv; w1 *= inv;
    float* op = O + (size_t)(b * Sn + qg) * Dn;
#pragma unroll
    for (int dt = 0; dt < 4; ++dt) {
#pragma unroll
      for (int q2 = 0; q2 < 4; ++q2) {
        const float4 o1 = *(const float4*)(xch + (dt * 4 + q2) * 1024 + lane * 16);
        float4 v;
        v.x = o[dt][4 * q2 + 0] * w0 + o1.x * w1;
        v.y = o[dt][4 * q2 + 1] * w0 + o1.y * w1;
        v.z = o[dt][4 * q2 + 2] * w0 + o1.z * w1;
        v.w = o[dt][4 * q2 + 3] * w0 + o1.w * w1;
        *(float4*)(op + dt * 32 + q2 * 8 + hi * 4) = v;
      }
    }
  }
}

extern "C" void kernel_launch(void* const* d_in, const int* in_sizes, int n_in,
                              void* d_out, int out_size, void* d_ws, size_t ws_size,
                              hipStream_t stream) {
  (void)in_sizes; (void)n_in; (void)d_ws; (void)ws_size; (void)out_size;
  const float* Q = (const float*)d_in[0];
  const float* K = (const float*)d_in[1];
  const float* V = (const float*)d_in[2];
  float* O = (float*)d_out;
  dim3 grid(Sn / QBLK, Bn, 1);
  attn_fwd<<<grid, dim3(NTHR, 1, 1), 0, stream>>>(Q, K, V, O);
}